// Round 1
// baseline (845.350 us; speedup 1.0000x reference)
//
#include <hip/hip_runtime.h>

#define HIDDEN 32
#define FOUR_H 128
#define FUT 6
#define BSZ 256
#define TT 2048
#define FF 64

__device__ __forceinline__ float fast_rcp(float x)  { return __builtin_amdgcn_rcpf(x); }
__device__ __forceinline__ float fast_exp2(float x) { return __builtin_amdgcn_exp2f(x); }
__device__ __forceinline__ float sigmoid_f(float x) {
    // 1/(1+exp(-x)) = 1/(1+exp2(-x*log2e))
    float t = fast_exp2(x * -1.44269504088896340736f);
    return fast_rcp(1.0f + t);
}

// ---------------------------------------------------------------------------
// Kernel 1: x_proj = X @ Wx + b for timesteps [t0, t0+cur)
// output layout: xg[b][tc][128] with tc = t - t0  (rows r = b*cur + tc)
// block: 256 threads, 64 rows x 128 cols per block
// ---------------------------------------------------------------------------
__global__ __launch_bounds__(256) void xproj_kernel(
    const float* __restrict__ X, const float* __restrict__ Wx,
    const float* __restrict__ bias, float* __restrict__ xg,
    int t0, int cur)
{
    __shared__ float sW[64][128];   // Wx, row-major [k][j]
    __shared__ float sX[64][65];    // X tile transposed [k][row], +1 pad

    int tid = threadIdx.x;
    long rowBase = (long)blockIdx.x * 64;

    // stage Wx (8192 floats = 2048 float4; 8 per thread)
    const float4* W4 = (const float4*)Wx;
    float4* sW4 = (float4*)&sW[0][0];
#pragma unroll
    for (int i = 0; i < 8; ++i) sW4[tid + 256 * i] = W4[tid + 256 * i];

    // stage X tile transposed (64 rows x 64 k = 1024 float4; 4 per thread)
#pragma unroll
    for (int i = 0; i < 4; ++i) {
        int idx = tid + 256 * i;
        int row = idx >> 4;
        int kq  = idx & 15;
        int r   = (int)rowBase + row;
        int bb  = r / cur;
        int tc  = r - bb * cur;
        const float4* xp = (const float4*)(X + ((long)bb * TT + t0 + tc) * FF);
        float4 v = xp[kq];
        sX[kq * 4 + 0][row] = v.x;
        sX[kq * 4 + 1][row] = v.y;
        sX[kq * 4 + 2][row] = v.z;
        sX[kq * 4 + 3][row] = v.w;
    }
    __syncthreads();

    int cq = tid & 31;   // column quad: cols 4*cq .. 4*cq+3
    int rg = tid >> 5;   // row group: rows 8*rg .. 8*rg+7

    float4 bv = *(const float4*)(bias + cq * 4);
    float4 acc[8];
#pragma unroll
    for (int i = 0; i < 8; ++i) acc[i] = bv;

#pragma unroll 8
    for (int k = 0; k < 64; ++k) {
        float4 w = *(const float4*)&sW[k][cq * 4];
#pragma unroll
        for (int i = 0; i < 8; ++i) {
            float x = sX[k][rg * 8 + i];
            acc[i].x = fmaf(x, w.x, acc[i].x);
            acc[i].y = fmaf(x, w.y, acc[i].y);
            acc[i].z = fmaf(x, w.z, acc[i].z);
            acc[i].w = fmaf(x, w.w, acc[i].w);
        }
    }

#pragma unroll
    for (int i = 0; i < 8; ++i) {
        long r = rowBase + rg * 8 + i;
        *(float4*)(xg + r * FOUR_H + cq * 4) = acc[i];
    }
}

// ---------------------------------------------------------------------------
// Kernel 2: sequential LSTM scan. One wave (64 threads) per batch element.
// lane l owns gate outputs j = l (i/f) and j = l+64 (g/o).
// lanes 0..31 and 32..63 both hold (c_k, h_k) for k = l & 31 (redundant).
// ---------------------------------------------------------------------------
__global__ __launch_bounds__(64) void lstm_rec_kernel(
    const float* __restrict__ xg, const float* __restrict__ Wh,
    const float* __restrict__ Wd, const float* __restrict__ bd,
    float* __restrict__ state, float* __restrict__ out,
    int cur, int first, int last)
{
    int b = blockIdx.x;
    int l = threadIdx.x;
    int kl = l & 31;
    bool lowHalf = (l < 32);

    // recurrent weights held in registers: Wh[k][l] and Wh[k][64+l]
    float wh0[32], wh1[32];
#pragma unroll
    for (int k = 0; k < 32; ++k) {
        wh0[k] = Wh[k * FOUR_H + l];
        wh1[k] = Wh[k * FOUR_H + 64 + l];
    }

    float c, h;
    if (first) { c = 0.0f; h = 0.0f; }
    else       { c = state[b * 64 + kl]; h = state[b * 64 + 32 + kl]; }

    const float* xp = xg + (size_t)b * cur * FOUR_H;

    // depth-4 prefetch ring for xg
    float z0[4], z1[4];
#pragma unroll
    for (int u = 0; u < 4; ++u) {
        if (u < cur) { z0[u] = xp[u * FOUR_H + l]; z1[u] = xp[u * FOUR_H + 64 + l]; }
        else         { z0[u] = 0.0f; z1[u] = 0.0f; }
    }

    // per-lane activation constants for A1 (g -> tanh on low half, o -> sigmoid on high half)
    const float L2E = 1.44269504088896340736f;
    float s1 = lowHalf ? (-2.0f * L2E) : (-L2E);  // exp2 scale
    float m1 = lowHalf ? 2.0f : 1.0f;             // post-scale
    float a1 = lowHalf ? -1.0f : 0.0f;            // post-offset

    int t = 0;

#define LSTM_STEP(U)                                                              \
    {                                                                             \
        float acc0a = z0[U], acc1a = z1[U];                                       \
        float acc0b = 0.0f, acc1b = 0.0f;                                         \
        _Pragma("unroll")                                                         \
        for (int k = 0; k < 32; k += 2) {                                         \
            float hk0 = __int_as_float(__builtin_amdgcn_readlane(__float_as_int(h), k));     \
            float hk1 = __int_as_float(__builtin_amdgcn_readlane(__float_as_int(h), k + 1)); \
            acc0a = fmaf(hk0, wh0[k], acc0a);                                     \
            acc1a = fmaf(hk0, wh1[k], acc1a);                                     \
            acc0b = fmaf(hk1, wh0[k + 1], acc0b);                                 \
            acc1b = fmaf(hk1, wh1[k + 1], acc1b);                                 \
        }                                                                         \
        float A0 = acc0a + acc0b;                                                 \
        float A1 = acc1a + acc1b;                                                 \
        float act0 = sigmoid_f(A0);                                               \
        float u1 = fast_rcp(1.0f + fast_exp2(A1 * s1));                           \
        float act1 = fmaf(u1, m1, a1);                                            \
        float act0x = __shfl_xor(act0, 32);                                       \
        float act1x = __shfl_xor(act1, 32);                                       \
        float gi = lowHalf ? act0  : act0x;                                       \
        float gf = lowHalf ? act0x : act0;                                        \
        float gg = lowHalf ? act1  : act1x;                                       \
        float go = lowHalf ? act1x : act1;                                        \
        c = fmaf(gf, c, gi * gg);                                                 \
        float uc = fast_rcp(1.0f + fast_exp2(c * -2.88539008177792681472f));      \
        float tc2 = fmaf(uc, 2.0f, -1.0f);                                        \
        h = go * tc2;                                                             \
        int tn = t + 4 + (U);                                                     \
        if (tn < cur) {                                                           \
            z0[U] = xp[tn * FOUR_H + l];                                          \
            z1[U] = xp[tn * FOUR_H + 64 + l];                                     \
        }                                                                         \
    }

    for (; t + 4 <= cur; t += 4) {
        LSTM_STEP(0)
        LSTM_STEP(1)
        LSTM_STEP(2)
        LSTM_STEP(3)
    }
    int rem = cur - t;
    if (rem > 0) LSTM_STEP(0)
    if (rem > 1) LSTM_STEP(1)
    if (rem > 2) LSTM_STEP(2)

#undef LSTM_STEP

    if (last) {
        // out = elu(h_T) @ Wd + bd
        float e = (h > 0.0f) ? h : (fast_exp2(h * L2E) - 1.0f);
#pragma unroll
        for (int q = 0; q < FUT; ++q) {
            float v = lowHalf ? e * Wd[kl * FUT + q] : 0.0f;
#pragma unroll
            for (int off = 1; off < 64; off <<= 1)
                v += __shfl_xor(v, off);
            if (l == 0) out[b * FUT + q] = v + bd[q];
        }
    } else {
        if (lowHalf) {
            state[b * 64 + kl]      = c;
            state[b * 64 + 32 + kl] = h;
        }
    }
}

// ---------------------------------------------------------------------------
extern "C" void kernel_launch(void* const* d_in, const int* in_sizes, int n_in,
                              void* d_out, int out_size, void* d_ws, size_t ws_size,
                              hipStream_t stream)
{
    const float* X    = (const float*)d_in[0];
    const float* Wx   = (const float*)d_in[1];
    const float* Wh   = (const float*)d_in[2];
    const float* bias = (const float*)d_in[3];
    const float* Wd   = (const float*)d_in[4];
    const float* bd   = (const float*)d_in[5];
    float* out = (float*)d_out;

    float* state = (float*)d_ws;
    size_t stateBytes = (size_t)BSZ * 64 * sizeof(float);
    float* xgbuf = (float*)((char*)d_ws + stateBytes);

    size_t avail = ws_size > stateBytes ? ws_size - stateBytes : 0;
    size_t perT = (size_t)BSZ * FOUR_H * sizeof(float);   // 128 KB per timestep
    long TcL = (long)(avail / perT);
    int Tc = (TcL > TT) ? TT : (int)TcL;
    if (Tc < 1) return;  // workspace too small to run

    for (int t0 = 0; t0 < TT; t0 += Tc) {
        int cur = (TT - t0 < Tc) ? (TT - t0) : Tc;
        int blocks = (BSZ * cur) / 64;   // 64 rows per block, always divides
        xproj_kernel<<<dim3(blocks), dim3(256), 0, stream>>>(X, Wx, bias, xgbuf, t0, cur);
        lstm_rec_kernel<<<dim3(BSZ), dim3(64), 0, stream>>>(
            xgbuf, Wh, Wd, bd, state, out, cur, (t0 == 0) ? 1 : 0,
            (t0 + cur >= TT) ? 1 : 0);
    }
}

// Round 2
// 635.357 us; speedup vs baseline: 1.3305x; 1.3305x over previous
//
#include <hip/hip_runtime.h>

#define HIDDEN 32
#define FOUR_H 128
#define FUT 6
#define BSZ 256
#define TT 2048
#define FF 64
#define CH 16                      // timesteps per LDS chunk
#define CHB (CH * FOUR_H * 4)      // 8192 bytes per chunk

__device__ __forceinline__ float fast_rcp(float x)  { return __builtin_amdgcn_rcpf(x); }
__device__ __forceinline__ float fast_exp2(float x) { return __builtin_amdgcn_exp2f(x); }
__device__ __forceinline__ float sigmoid_f(float x) {
    float t = fast_exp2(x * -1.44269504088896340736f);
    return fast_rcp(1.0f + t);
}

__device__ __forceinline__ void gload_lds16(const void* g, void* l) {
    __builtin_amdgcn_global_load_lds(
        (const __attribute__((address_space(1))) void*)g,
        (__attribute__((address_space(3))) void*)l, 16, 0, 0);
}

// ---------------------------------------------------------------------------
// Kernel 1: x_proj = X @ Wx + b for timesteps [t0, t0+cur)
// output layout: xg[b][tc][128], rows r = b*cur + tc
// ---------------------------------------------------------------------------
__global__ __launch_bounds__(256) void xproj_kernel(
    const float* __restrict__ X, const float* __restrict__ Wx,
    const float* __restrict__ bias, float* __restrict__ xg,
    int t0, int cur)
{
    __shared__ float sW[64][128];
    __shared__ float sX[64][65];

    int tid = threadIdx.x;
    long rowBase = (long)blockIdx.x * 64;

    const float4* W4 = (const float4*)Wx;
    float4* sW4 = (float4*)&sW[0][0];
#pragma unroll
    for (int i = 0; i < 8; ++i) sW4[tid + 256 * i] = W4[tid + 256 * i];

#pragma unroll
    for (int i = 0; i < 4; ++i) {
        int idx = tid + 256 * i;
        int row = idx >> 4;
        int kq  = idx & 15;
        int r   = (int)rowBase + row;
        int bb  = r / cur;
        int tc  = r - bb * cur;
        const float4* xp = (const float4*)(X + ((long)bb * TT + t0 + tc) * FF);
        float4 v = xp[kq];
        sX[kq * 4 + 0][row] = v.x;
        sX[kq * 4 + 1][row] = v.y;
        sX[kq * 4 + 2][row] = v.z;
        sX[kq * 4 + 3][row] = v.w;
    }
    __syncthreads();

    int cq = tid & 31;
    int rg = tid >> 5;

    float4 bv = *(const float4*)(bias + cq * 4);
    float4 acc[8];
#pragma unroll
    for (int i = 0; i < 8; ++i) acc[i] = bv;

#pragma unroll 8
    for (int k = 0; k < 64; ++k) {
        float4 w = *(const float4*)&sW[k][cq * 4];
#pragma unroll
        for (int i = 0; i < 8; ++i) {
            float x = sX[k][rg * 8 + i];
            acc[i].x = fmaf(x, w.x, acc[i].x);
            acc[i].y = fmaf(x, w.y, acc[i].y);
            acc[i].z = fmaf(x, w.z, acc[i].z);
            acc[i].w = fmaf(x, w.w, acc[i].w);
        }
    }

#pragma unroll
    for (int i = 0; i < 8; ++i) {
        long r = rowBase + rg * 8 + i;
        *(float4*)(xg + r * FOUR_H + cq * 4) = acc[i];
    }
}

// ---------------------------------------------------------------------------
// Kernel 2: sequential LSTM scan. One wave per batch element.
// xg is streamed global -> LDS (double-buffered, 16-step chunks) via
// global_load_lds with counted vmcnt; z reads are ds_read_b32 (2-way = free).
// ---------------------------------------------------------------------------
__global__ __launch_bounds__(64) void lstm_rec_kernel(
    const float* __restrict__ xg, const float* __restrict__ Wh,
    const float* __restrict__ Wd, const float* __restrict__ bd,
    float* __restrict__ state, float* __restrict__ out,
    int cur, int first, int last)
{
    __shared__ float sxg[2 * CH * FOUR_H];   // 16 KB double buffer

    int b = blockIdx.x;
    int l = threadIdx.x;
    int kl = l & 31;
    bool lowHalf = (l < 32);

    float wh0[32], wh1[32];
#pragma unroll
    for (int k = 0; k < 32; ++k) {
        wh0[k] = Wh[k * FOUR_H + l];
        wh1[k] = Wh[k * FOUR_H + 64 + l];
    }

    float c, h;
    if (first) { c = 0.0f; h = 0.0f; }
    else       { c = state[b * 64 + kl]; h = state[b * 64 + 32 + kl]; }

    const char* xpc = (const char*)(xg + (size_t)b * cur * FOUR_H);

    const float L2E = 1.44269504088896340736f;
    float s1 = lowHalf ? (-2.0f * L2E) : (-L2E);
    float m1 = lowHalf ? 2.0f : 1.0f;
    float a1 = lowHalf ? -1.0f : 0.0f;

#define ISSUE_CHUNK(nn)                                                      \
    {                                                                        \
        const char* src = xpc + (size_t)(nn) * CHB + l * 16;                 \
        char* dstb = (char*)sxg + ((nn) & 1) * CHB;                          \
        _Pragma("unroll")                                                    \
        for (int i = 0; i < 8; ++i)                                          \
            gload_lds16(src + i * 1024, dstb + i * 1024);                    \
    }

#define STEP_BODY(Z0, Z1)                                                    \
    {                                                                        \
        float acc0a = (Z0), acc1a = (Z1);                                    \
        float acc0b = 0.0f, acc1b = 0.0f;                                    \
        _Pragma("unroll")                                                    \
        for (int k = 0; k < 32; k += 2) {                                    \
            float hk0 = __int_as_float(__builtin_amdgcn_readlane(__float_as_int(h), k));     \
            float hk1 = __int_as_float(__builtin_amdgcn_readlane(__float_as_int(h), k + 1)); \
            acc0a = fmaf(hk0, wh0[k], acc0a);                                \
            acc1a = fmaf(hk0, wh1[k], acc1a);                                \
            acc0b = fmaf(hk1, wh0[k + 1], acc0b);                            \
            acc1b = fmaf(hk1, wh1[k + 1], acc1b);                            \
        }                                                                    \
        float A0 = acc0a + acc0b;                                            \
        float A1 = acc1a + acc1b;                                            \
        float act0 = sigmoid_f(A0);                                          \
        float u1 = fast_rcp(1.0f + fast_exp2(A1 * s1));                      \
        float act1 = fmaf(u1, m1, a1);                                       \
        float act0x = __shfl_xor(act0, 32);                                  \
        float act1x = __shfl_xor(act1, 32);                                  \
        float gi = lowHalf ? act0  : act0x;                                  \
        float gf = lowHalf ? act0x : act0;                                   \
        float gg = lowHalf ? act1  : act1x;                                  \
        float go = lowHalf ? act1x : act1;                                   \
        c = fmaf(gf, c, gi * gg);                                            \
        float uc = fast_rcp(1.0f + fast_exp2(c * -2.88539008177792681472f)); \
        float tc2 = fmaf(uc, 2.0f, -1.0f);                                   \
        h = go * tc2;                                                        \
    }

    int nFull = cur / CH;

    if (nFull > 0) {
        ISSUE_CHUNK(0)
        for (int n = 0; n < nFull; ++n) {
            if (n + 1 < nFull) {
                ISSUE_CHUNK(n + 1)
                asm volatile("s_waitcnt vmcnt(8)" ::: "memory");
            } else {
                asm volatile("s_waitcnt vmcnt(0)" ::: "memory");
            }
            int bufOff = (n & 1) * (CH * FOUR_H);
#pragma unroll
            for (int tc = 0; tc < CH; ++tc) {
                float z0 = sxg[bufOff + tc * FOUR_H + l];
                float z1 = sxg[bufOff + tc * FOUR_H + 64 + l];
                STEP_BODY(z0, z1)
            }
        }
    }

    // tail (cur not a multiple of CH): direct global reads, latency-tolerant
    for (int t = nFull * CH; t < cur; ++t) {
        const float* xrow = (const float*)xpc + (size_t)t * FOUR_H;
        float z0 = xrow[l];
        float z1 = xrow[64 + l];
        STEP_BODY(z0, z1)
    }

#undef STEP_BODY
#undef ISSUE_CHUNK

    if (last) {
        float e = (h > 0.0f) ? h : (fast_exp2(h * L2E) - 1.0f);
#pragma unroll
        for (int q = 0; q < FUT; ++q) {
            float v = lowHalf ? e * Wd[kl * FUT + q] : 0.0f;
#pragma unroll
            for (int off = 1; off < 64; off <<= 1)
                v += __shfl_xor(v, off);
            if (l == 0) out[b * FUT + q] = v + bd[q];
        }
    } else {
        if (lowHalf) {
            state[b * 64 + kl]      = c;
            state[b * 64 + 32 + kl] = h;
        }
    }
}

// ---------------------------------------------------------------------------
extern "C" void kernel_launch(void* const* d_in, const int* in_sizes, int n_in,
                              void* d_out, int out_size, void* d_ws, size_t ws_size,
                              hipStream_t stream)
{
    const float* X    = (const float*)d_in[0];
    const float* Wx   = (const float*)d_in[1];
    const float* Wh   = (const float*)d_in[2];
    const float* bias = (const float*)d_in[3];
    const float* Wd   = (const float*)d_in[4];
    const float* bd   = (const float*)d_in[5];
    float* out = (float*)d_out;

    float* state = (float*)d_ws;
    size_t stateBytes = (size_t)BSZ * 64 * sizeof(float);
    float* xgbuf = (float*)((char*)d_ws + stateBytes);

    size_t avail = ws_size > stateBytes ? ws_size - stateBytes : 0;
    size_t perT = (size_t)BSZ * FOUR_H * sizeof(float);
    long TcL = (long)(avail / perT);
    int Tc = (TcL > TT) ? TT : (int)TcL;
    if (Tc < 1) return;

    for (int t0 = 0; t0 < TT; t0 += Tc) {
        int cur = (TT - t0 < Tc) ? (TT - t0) : Tc;
        int blocks = (BSZ * cur) / 64;
        xproj_kernel<<<dim3(blocks), dim3(256), 0, stream>>>(X, Wx, bias, xgbuf, t0, cur);
        lstm_rec_kernel<<<dim3(BSZ), dim3(64), 0, stream>>>(
            xgbuf, Wh, Wd, bd, state, out, cur, (t0 == 0) ? 1 : 0,
            (t0 + cur >= TT) ? 1 : 0);
    }
}